// Round 8
// baseline (57.562 us; speedup 1.0000x reference)
//
#include <hip/hip_runtime.h>
#include <hip/hip_fp16.h>
#include <math.h>

// f(x) = tanh-MLP(x), 1->16->32->32->16->3, per scalar element.
// R8 = R6 (known-pass) with apply_s launched TWICE (identical work/output).
// Purpose: measurement. dur_R8 - dur_R6 = true apply duration, independent
// of any fixed harness floor; a ~38us apply would also surface in rocprof
// top-5 with full counters.

#define TN 2048
#define XLO (-10.0f)
#define XHI (10.0f)

__device__ __forceinline__ float fast_tanh(float x) {
    float t = __builtin_amdgcn_exp2f(x * 2.885390081777927f);
    return 1.0f - 2.0f * __builtin_amdgcn_rcpf(t + 1.0f);
}

__global__ __launch_bounds__(128) void build_table(
    const float* __restrict__ W0, const float* __restrict__ b0,
    const float* __restrict__ W1, const float* __restrict__ b1,
    const float* __restrict__ W2, const float* __restrict__ b2,
    const float* __restrict__ W3, const float* __restrict__ b3,
    const float* __restrict__ W4, const float* __restrict__ b4,
    unsigned* __restrict__ tab_g)
{
    __shared__ __align__(16) float w[2224];
    __shared__ float4 o_lds[65];
    const int t = threadIdx.x;

    for (int i = t; i < 16;  i += 128) { w[i] = W0[i]; w[16 + i] = b0[i]; }
    for (int i = t; i < 512; i += 128) { int k = i >> 5, j = i & 31; w[32   + j * 16 + k] = W1[i]; }
    for (int i = t; i < 32;  i += 128) w[544  + i] = b1[i];
    for (int i = t; i < 1024;i += 128) { int k = i >> 5, j = i & 31; w[576  + j * 32 + k] = W2[i]; }
    for (int i = t; i < 32;  i += 128) w[1600 + i] = b2[i];
    for (int i = t; i < 512; i += 128) { int k = i >> 4, j = i & 15; w[1632 + j * 32 + k] = W3[i]; }
    for (int i = t; i < 16;  i += 128) w[2144 + i] = b3[i];
    for (int i = t; i < 48;  i += 128) { int k = i / 3, j = i - 3 * k; w[2160 + j * 16 + k] = W4[i]; }
    if (t < 3) w[2208 + t] = b4[t];
    __syncthreads();

    const int base = blockIdx.x * 64;
    if (t <= 64) {
        int cp = min(base + t, TN - 1);
        const float h = (XHI - XLO) / (float)(TN - 1);
        const float x = XLO + (float)cp * h;
        const float4* L4 = (const float4*)w;

        float a[32], c[32];
        #pragma unroll
        for (int q = 0; q < 4; ++q) {
            float4 wq = L4[q];
            float4 bq = L4[4 + q];
            a[4 * q + 0] = fast_tanh(fmaf(x, wq.x, bq.x));
            a[4 * q + 1] = fast_tanh(fmaf(x, wq.y, bq.y));
            a[4 * q + 2] = fast_tanh(fmaf(x, wq.z, bq.z));
            a[4 * q + 3] = fast_tanh(fmaf(x, wq.w, bq.w));
        }
        #pragma unroll
        for (int j = 0; j < 32; ++j) {
            float acc = w[544 + j];
            #pragma unroll
            for (int q = 0; q < 4; ++q) {
                float4 wq = L4[8 + j * 4 + q];
                acc = fmaf(a[4 * q + 0], wq.x, acc);
                acc = fmaf(a[4 * q + 1], wq.y, acc);
                acc = fmaf(a[4 * q + 2], wq.z, acc);
                acc = fmaf(a[4 * q + 3], wq.w, acc);
            }
            c[j] = fast_tanh(acc);
        }
        #pragma unroll
        for (int j = 0; j < 32; ++j) {
            float acc = w[1600 + j];
            #pragma unroll
            for (int q = 0; q < 8; ++q) {
                float4 wq = L4[144 + j * 8 + q];
                acc = fmaf(c[4 * q + 0], wq.x, acc);
                acc = fmaf(c[4 * q + 1], wq.y, acc);
                acc = fmaf(c[4 * q + 2], wq.z, acc);
                acc = fmaf(c[4 * q + 3], wq.w, acc);
            }
            a[j] = fast_tanh(acc);
        }
        #pragma unroll
        for (int j = 0; j < 16; ++j) {
            float acc = w[2144 + j];
            #pragma unroll
            for (int q = 0; q < 8; ++q) {
                float4 wq = L4[408 + j * 8 + q];
                acc = fmaf(a[4 * q + 0], wq.x, acc);
                acc = fmaf(a[4 * q + 1], wq.y, acc);
                acc = fmaf(a[4 * q + 2], wq.z, acc);
                acc = fmaf(a[4 * q + 3], wq.w, acc);
            }
            c[j] = fast_tanh(acc);
        }
        float o[3];
        #pragma unroll
        for (int j = 0; j < 3; ++j) {
            float acc = w[2208 + j];
            #pragma unroll
            for (int q = 0; q < 4; ++q) {
                float4 wq = L4[540 + j * 4 + q];
                acc = fmaf(c[4 * q + 0], wq.x, acc);
                acc = fmaf(c[4 * q + 1], wq.y, acc);
                acc = fmaf(c[4 * q + 2], wq.z, acc);
                acc = fmaf(c[4 * q + 3], wq.w, acc);
            }
            o[j] = fast_tanh(acc);
        }
        o_lds[t] = make_float4(o[0], o[1], o[2], 0.0f);
    }
    __syncthreads();

    if (t < 64) {
        float4 lo = o_lds[t];
        float4 hi = o_lds[t + 1];
        __half2 p0 = __floats2half2_rn(lo.x, hi.x);   // .x=f(i), .y=f(i+1)
        __half2 p1 = __floats2half2_rn(lo.y, hi.y);
        __half2 p2 = __floats2half2_rn(lo.z, hi.z);
        tab_g[         base + t] = *reinterpret_cast<unsigned*>(&p0);
        tab_g[TN     + base + t] = *reinterpret_cast<unsigned*>(&p1);
        tab_g[2 * TN + base + t] = *reinterpret_cast<unsigned*>(&p2);
    }
}

__device__ __forceinline__ void lerp3s(
    const unsigned* __restrict__ t0, const unsigned* __restrict__ t1,
    const unsigned* __restrict__ t2, float inv_h, float x,
    float& y0, float& y1, float& y2)
{
    float xc = fminf(fmaxf(x, XLO), XHI);
    float f  = (xc - XLO) * inv_h;
    int i0 = (int)f;
    i0 = min(i0, TN - 2);
    float fr = f - (float)i0;
    unsigned e0 = t0[i0];
    unsigned e1 = t1[i0];
    unsigned e2 = t2[i0];
    float2 p0 = __half22float2(*reinterpret_cast<__half2*>(&e0));
    float2 p1 = __half22float2(*reinterpret_cast<__half2*>(&e1));
    float2 p2 = __half22float2(*reinterpret_cast<__half2*>(&e2));
    y0 = fmaf(fr, p0.y - p0.x, p0.x);
    y1 = fmaf(fr, p1.y - p1.x, p1.x);
    y2 = fmaf(fr, p2.y - p2.x, p2.x);
}

__global__ __launch_bounds__(256) void apply_s(
    const float* __restrict__ x, const unsigned* __restrict__ tab_g,
    float4* __restrict__ out4, unsigned n_out4)
{
    __shared__ unsigned t0[TN];
    __shared__ unsigned t1[TN];
    __shared__ unsigned t2[TN];
    for (int i = threadIdx.x; i < TN; i += 256) {
        t0[i] = tab_g[i];
        t1[i] = tab_g[TN + i];
        t2[i] = tab_g[2 * TN + i];
    }
    __syncthreads();

    const float inv_h = (float)(TN - 1) / (XHI - XLO);
    unsigned stride = gridDim.x * 256u;
    for (unsigned g = blockIdx.x * 256u + threadIdx.x; g < n_out4; g += stride) {
        unsigned e = (4u * g) / 3u;
        unsigned r = 4u * g - 3u * e;
        float x0 = x[e];
        float x1 = x[e + 1];
        float s0, s1, s2, s3, s4, s5;
        lerp3s(t0, t1, t2, inv_h, x0, s0, s1, s2);
        lerp3s(t0, t1, t2, inv_h, x1, s3, s4, s5);
        float4 o;
        o.x = (r == 0u) ? s0 : ((r == 1u) ? s1 : s2);
        o.y = (r == 0u) ? s1 : ((r == 1u) ? s2 : s3);
        o.z = (r == 0u) ? s2 : ((r == 1u) ? s3 : s4);
        o.w = (r == 0u) ? s3 : ((r == 1u) ? s4 : s5);
        out4[g] = o;
    }
}

extern "C" void kernel_launch(void* const* d_in, const int* in_sizes, int n_in,
                              void* d_out, int out_size, void* d_ws, size_t ws_size,
                              hipStream_t stream) {
    const float* x  = (const float*)d_in[0];
    const float* W0 = (const float*)d_in[1];
    const float* b0 = (const float*)d_in[2];
    const float* W1 = (const float*)d_in[3];
    const float* b1 = (const float*)d_in[4];
    const float* W2 = (const float*)d_in[5];
    const float* b2 = (const float*)d_in[6];
    const float* W3 = (const float*)d_in[7];
    const float* b3 = (const float*)d_in[8];
    const float* W4 = (const float*)d_in[9];
    const float* b4 = (const float*)d_in[10];
    unsigned* tab = (unsigned*)d_ws;   // 24 KB scratch

    build_table<<<TN / 64, 128, 0, stream>>>(
        W0, b0, W1, b1, W2, b2, W3, b3, W4, b4, tab);

    unsigned n_out4 = (unsigned)out_size / 4u;   // 3145728
    int blocks = 1536;                           // 6 blocks/CU (24KB LDS)
    // Launch TWICE: identical work and output (deterministic). The dur_us
    // delta vs R6 isolates the true apply duration from any fixed floor.
    apply_s<<<blocks, 256, 0, stream>>>(x, tab, (float4*)d_out, n_out4);
    apply_s<<<blocks, 256, 0, stream>>>(x, tab, (float4*)d_out, n_out4);
}

// Round 9
// 26.431 us; speedup vs baseline: 2.1778x; 2.1778x over previous
//
#include <hip/hip_runtime.h>
#include <hip/hip_fp16.h>
#include <math.h>

// f(x) = tanh-MLP(x), 1->16->32->32->16->3, per scalar element.
// R9: build_table rebuilt as WAVE-PER-ENTRY, NEURON-PER-LANE (the old
// thread-per-point build was latency-bound ~27us: ~530 dependent loads x
// ~120cy on 2 waves/CU x 32 CUs -- the real hidden cost all 6 rounds).
//   - 2048 entry-waves = 512 blocks x 256 thr (full GPU)
//   - lanes 0-31: point e, lanes 32-63: point e+1; one neuron per lane
//   - activations via width-32 __shfl; weights raw row-major in LDS
//     (per-k reads are lane-contiguous; halves broadcast -> conflict-free)
// apply_s: exact R6 kernel (measured 13.6us via the R8 double-launch probe).

#define TN 2048
#define XLO (-10.0f)
#define XHI (10.0f)

__device__ __forceinline__ float fast_tanh(float x) {
    float t = __builtin_amdgcn_exp2f(x * 2.885390081777927f);
    return 1.0f - 2.0f * __builtin_amdgcn_rcpf(t + 1.0f);
}

// LDS float layout (raw row-major, straight copy):
//   W0@0[16] b0@16[16] W1@32[16][32] b1@544[32] W2@576[32][32] b2@1600[32]
//   W3@1632[32][16] b3@2144[16] W4@2160[16][3] b4@2208[3]   (2211 floats)
__global__ __launch_bounds__(256) void build_table(
    const float* __restrict__ W0, const float* __restrict__ b0,
    const float* __restrict__ W1, const float* __restrict__ b1,
    const float* __restrict__ W2, const float* __restrict__ b2,
    const float* __restrict__ W3, const float* __restrict__ b3,
    const float* __restrict__ W4, const float* __restrict__ b4,
    unsigned* __restrict__ tab_g)
{
    __shared__ float w[2211];
    const int t = threadIdx.x;

    for (int i = t; i < 16;   i += 256) { w[i] = W0[i]; w[16 + i] = b0[i]; }
    for (int i = t; i < 512;  i += 256) w[32   + i] = W1[i];
    for (int i = t; i < 32;   i += 256) w[544  + i] = b1[i];
    for (int i = t; i < 1024; i += 256) w[576  + i] = W2[i];
    for (int i = t; i < 32;   i += 256) w[1600 + i] = b2[i];
    for (int i = t; i < 512;  i += 256) w[1632 + i] = W3[i];
    for (int i = t; i < 16;   i += 256) w[2144 + i] = b3[i];
    for (int i = t; i < 48;   i += 256) w[2160 + i] = W4[i];
    if (t < 3) w[2208 + t] = b4[t];
    __syncthreads();

    const int wave = t >> 6;                  // 0..3
    const int half = (t >> 5) & 1;            // 0: point e, 1: point e+1
    const int sub  = t & 31;                  // neuron lane
    const int s16  = (sub < 15) ? sub : 15;
    const int e    = blockIdx.x * 4 + wave;   // entry index, < TN
    const int p    = min(e + half, TN - 1);   // table point for this half

    const float h = (XHI - XLO) / (float)(TN - 1);
    const float x = XLO + (float)p * h;

    // L0: 1 -> 16 (lane sub = neuron sub; sub>=16 duplicates neuron 15)
    float act = fast_tanh(fmaf(x, w[s16], w[16 + s16]));

    // L1: 16 -> 32
    {
        float acc = w[544 + sub];
        #pragma unroll
        for (int k = 0; k < 16; ++k) {
            float ak = __shfl(act, k, 32);
            acc = fmaf(ak, w[32 + k * 32 + sub], acc);
        }
        act = fast_tanh(acc);
    }
    // L2: 32 -> 32
    {
        float acc = w[1600 + sub];
        #pragma unroll
        for (int k = 0; k < 32; ++k) {
            float ak = __shfl(act, k, 32);
            acc = fmaf(ak, w[576 + k * 32 + sub], acc);
        }
        act = fast_tanh(acc);
    }
    // L3: 32 -> 16 (sub>=16 duplicates neuron 15)
    {
        float acc = w[2144 + s16];
        #pragma unroll
        for (int k = 0; k < 32; ++k) {
            float ak = __shfl(act, k, 32);
            acc = fmaf(ak, w[1632 + k * 16 + s16], acc);
        }
        act = fast_tanh(acc);
    }
    // L4: 16 -> 3 (every lane computes all 3 outputs)
    float o0 = w[2208], o1 = w[2209], o2 = w[2210];
    #pragma unroll
    for (int k = 0; k < 16; ++k) {
        float ak = __shfl(act, k, 32);
        o0 = fmaf(ak, w[2160 + k * 3 + 0], o0);
        o1 = fmaf(ak, w[2160 + k * 3 + 1], o1);
        o2 = fmaf(ak, w[2160 + k * 3 + 2], o2);
    }
    o0 = fast_tanh(o0); o1 = fast_tanh(o1); o2 = fast_tanh(o2);

    // lane 32 holds point e+1's outputs; bring to the whole wave
    float h0 = __shfl(o0, 32, 64);
    float h1 = __shfl(o1, 32, 64);
    float h2 = __shfl(o2, 32, 64);

    if ((t & 63) == 0) {                      // wave lane 0 writes the entry
        __half2 p0 = __floats2half2_rn(o0, h0);   // .x=f(e), .y=f(e+1)
        __half2 p1 = __floats2half2_rn(o1, h1);
        __half2 p2 = __floats2half2_rn(o2, h2);
        tab_g[         e] = *reinterpret_cast<unsigned*>(&p0);
        tab_g[TN     + e] = *reinterpret_cast<unsigned*>(&p1);
        tab_g[2 * TN + e] = *reinterpret_cast<unsigned*>(&p2);
    }
}

__device__ __forceinline__ void lerp3s(
    const unsigned* __restrict__ t0, const unsigned* __restrict__ t1,
    const unsigned* __restrict__ t2, float inv_h, float x,
    float& y0, float& y1, float& y2)
{
    float xc = fminf(fmaxf(x, XLO), XHI);
    float f  = (xc - XLO) * inv_h;
    int i0 = (int)f;
    i0 = min(i0, TN - 2);
    float fr = f - (float)i0;
    unsigned e0 = t0[i0];
    unsigned e1 = t1[i0];
    unsigned e2 = t2[i0];
    float2 p0 = __half22float2(*reinterpret_cast<__half2*>(&e0));
    float2 p1 = __half22float2(*reinterpret_cast<__half2*>(&e1));
    float2 p2 = __half22float2(*reinterpret_cast<__half2*>(&e2));
    y0 = fmaf(fr, p0.y - p0.x, p0.x);
    y1 = fmaf(fr, p1.y - p1.x, p1.x);
    y2 = fmaf(fr, p2.y - p2.x, p2.x);
}

__global__ __launch_bounds__(256) void apply_s(
    const float* __restrict__ x, const unsigned* __restrict__ tab_g,
    float4* __restrict__ out4, unsigned n_out4)
{
    __shared__ unsigned t0[TN];
    __shared__ unsigned t1[TN];
    __shared__ unsigned t2[TN];
    for (int i = threadIdx.x; i < TN; i += 256) {
        t0[i] = tab_g[i];
        t1[i] = tab_g[TN + i];
        t2[i] = tab_g[2 * TN + i];
    }
    __syncthreads();

    const float inv_h = (float)(TN - 1) / (XHI - XLO);
    unsigned stride = gridDim.x * 256u;
    for (unsigned g = blockIdx.x * 256u + threadIdx.x; g < n_out4; g += stride) {
        unsigned e = (4u * g) / 3u;
        unsigned r = 4u * g - 3u * e;
        float x0 = x[e];
        float x1 = x[e + 1];
        float s0, s1, s2, s3, s4, s5;
        lerp3s(t0, t1, t2, inv_h, x0, s0, s1, s2);
        lerp3s(t0, t1, t2, inv_h, x1, s3, s4, s5);
        float4 o;
        o.x = (r == 0u) ? s0 : ((r == 1u) ? s1 : s2);
        o.y = (r == 0u) ? s1 : ((r == 1u) ? s2 : s3);
        o.z = (r == 0u) ? s2 : ((r == 1u) ? s3 : s4);
        o.w = (r == 0u) ? s3 : ((r == 1u) ? s4 : s5);
        out4[g] = o;
    }
}

extern "C" void kernel_launch(void* const* d_in, const int* in_sizes, int n_in,
                              void* d_out, int out_size, void* d_ws, size_t ws_size,
                              hipStream_t stream) {
    const float* x  = (const float*)d_in[0];
    const float* W0 = (const float*)d_in[1];
    const float* b0 = (const float*)d_in[2];
    const float* W1 = (const float*)d_in[3];
    const float* b1 = (const float*)d_in[4];
    const float* W2 = (const float*)d_in[5];
    const float* b2 = (const float*)d_in[6];
    const float* W3 = (const float*)d_in[7];
    const float* b3 = (const float*)d_in[8];
    const float* W4 = (const float*)d_in[9];
    const float* b4 = (const float*)d_in[10];
    unsigned* tab = (unsigned*)d_ws;   // 3*TN*4 = 24 KB scratch

    // 2048 entries, one wave each: 512 blocks x 256 threads (4 waves/block)
    build_table<<<TN / 4, 256, 0, stream>>>(
        W0, b0, W1, b1, W2, b2, W3, b3, W4, b4, tab);

    unsigned n_out4 = (unsigned)out_size / 4u;   // 3145728
    int blocks = 1536;                           // 6 blocks/CU (24KB LDS)
    apply_s<<<blocks, 256, 0, stream>>>(
        x, tab, (float4*)d_out, n_out4);
}

// Round 10
// 23.879 us; speedup vs baseline: 2.4105x; 1.1069x over previous
//
#include <hip/hip_runtime.h>
#include <hip/hip_fp16.h>
#include <math.h>

// f(x) = tanh-MLP(x), 1->16->32->32->16->3, per scalar element.
// R10 = R9 (wave-per-entry build, neuron-per-lane) with:
//   build: 4-way split accumulators (serial fma chain 32 -> 8 + tree reduce),
//          batched shfl issue, float4 weight staging.
//   apply: nontemporal 16B output stores (50MB stream, never re-read),
//          uint4 table staging.

#define TN 2048
#define XLO (-10.0f)
#define XHI (10.0f)

typedef float f32x4 __attribute__((ext_vector_type(4)));

__device__ __forceinline__ float fast_tanh(float x) {
    float t = __builtin_amdgcn_exp2f(x * 2.885390081777927f);
    return 1.0f - 2.0f * __builtin_amdgcn_rcpf(t + 1.0f);
}

// LDS float layout (raw row-major):
//   W0@0[16] b0@16[16] W1@32[16][32] b1@544[32] W2@576[32][32] b2@1600[32]
//   W3@1632[32][16] b3@2144[16] W4@2160[16][3] b4@2208[3]
__global__ __launch_bounds__(256) void build_table(
    const float* __restrict__ W0, const float* __restrict__ b0,
    const float* __restrict__ W1, const float* __restrict__ b1,
    const float* __restrict__ W2, const float* __restrict__ b2,
    const float* __restrict__ W3, const float* __restrict__ b3,
    const float* __restrict__ W4, const float* __restrict__ b4,
    unsigned* __restrict__ tab_g)
{
    __shared__ __align__(16) float w[2212];
    const int t = threadIdx.x;
    float4* w4 = (float4*)w;

    // float4 staging (all segment offsets 16B-aligned)
    if (t < 4)   w4[t]       = ((const float4*)W0)[t];
    if (t < 4)   w4[4 + t]   = ((const float4*)b0)[t];
    if (t < 128) w4[8 + t]   = ((const float4*)W1)[t];
    if (t < 8)   w4[136 + t] = ((const float4*)b1)[t];
    w4[144 + t] = ((const float4*)W2)[t];               // 256 float4s
    if (t < 8)   w4[400 + t] = ((const float4*)b2)[t];
    if (t < 128) w4[408 + t] = ((const float4*)W3)[t];
    if (t < 4)   w4[536 + t] = ((const float4*)b3)[t];
    if (t < 12)  w4[540 + t] = ((const float4*)W4)[t];
    if (t < 3)   w[2208 + t] = b4[t];
    __syncthreads();

    const int wave = t >> 6;                  // 0..3
    const int half = (t >> 5) & 1;            // 0: point e, 1: point e+1
    const int sub  = t & 31;                  // neuron lane
    const int s16  = (sub < 15) ? sub : 15;
    const int e    = blockIdx.x * 4 + wave;   // entry index, < TN
    const int p    = min(e + half, TN - 1);

    const float h = (XHI - XLO) / (float)(TN - 1);
    const float x = XLO + (float)p * h;

    // L0: 1 -> 16
    float act = fast_tanh(fmaf(x, w[s16], w[16 + s16]));

    // L1: 16 -> 32   (4-way split accumulators)
    {
        float acc0 = w[544 + sub], acc1 = 0.f, acc2 = 0.f, acc3 = 0.f;
        #pragma unroll
        for (int k = 0; k < 16; k += 4) {
            float a0 = __shfl(act, k + 0, 32);
            float a1 = __shfl(act, k + 1, 32);
            float a2 = __shfl(act, k + 2, 32);
            float a3 = __shfl(act, k + 3, 32);
            acc0 = fmaf(a0, w[32 + (k + 0) * 32 + sub], acc0);
            acc1 = fmaf(a1, w[32 + (k + 1) * 32 + sub], acc1);
            acc2 = fmaf(a2, w[32 + (k + 2) * 32 + sub], acc2);
            acc3 = fmaf(a3, w[32 + (k + 3) * 32 + sub], acc3);
        }
        act = fast_tanh((acc0 + acc1) + (acc2 + acc3));
    }
    // L2: 32 -> 32
    {
        float acc0 = w[1600 + sub], acc1 = 0.f, acc2 = 0.f, acc3 = 0.f;
        #pragma unroll
        for (int k = 0; k < 32; k += 4) {
            float a0 = __shfl(act, k + 0, 32);
            float a1 = __shfl(act, k + 1, 32);
            float a2 = __shfl(act, k + 2, 32);
            float a3 = __shfl(act, k + 3, 32);
            acc0 = fmaf(a0, w[576 + (k + 0) * 32 + sub], acc0);
            acc1 = fmaf(a1, w[576 + (k + 1) * 32 + sub], acc1);
            acc2 = fmaf(a2, w[576 + (k + 2) * 32 + sub], acc2);
            acc3 = fmaf(a3, w[576 + (k + 3) * 32 + sub], acc3);
        }
        act = fast_tanh((acc0 + acc1) + (acc2 + acc3));
    }
    // L3: 32 -> 16
    {
        float acc0 = w[2144 + s16], acc1 = 0.f, acc2 = 0.f, acc3 = 0.f;
        #pragma unroll
        for (int k = 0; k < 32; k += 4) {
            float a0 = __shfl(act, k + 0, 32);
            float a1 = __shfl(act, k + 1, 32);
            float a2 = __shfl(act, k + 2, 32);
            float a3 = __shfl(act, k + 3, 32);
            acc0 = fmaf(a0, w[1632 + (k + 0) * 16 + s16], acc0);
            acc1 = fmaf(a1, w[1632 + (k + 1) * 16 + s16], acc1);
            acc2 = fmaf(a2, w[1632 + (k + 2) * 16 + s16], acc2);
            acc3 = fmaf(a3, w[1632 + (k + 3) * 16 + s16], acc3);
        }
        act = fast_tanh((acc0 + acc1) + (acc2 + acc3));
    }
    // L4: 16 -> 3 (3 independent chains = 3-way ILP already)
    float o0 = w[2208], o1 = w[2209], o2 = w[2210];
    #pragma unroll
    for (int k = 0; k < 16; ++k) {
        float ak = __shfl(act, k, 32);
        o0 = fmaf(ak, w[2160 + k * 3 + 0], o0);
        o1 = fmaf(ak, w[2160 + k * 3 + 1], o1);
        o2 = fmaf(ak, w[2160 + k * 3 + 2], o2);
    }
    o0 = fast_tanh(o0); o1 = fast_tanh(o1); o2 = fast_tanh(o2);

    // lane 32 holds point e+1's outputs
    float h0 = __shfl(o0, 32, 64);
    float h1 = __shfl(o1, 32, 64);
    float h2 = __shfl(o2, 32, 64);

    if ((t & 63) == 0) {
        __half2 p0 = __floats2half2_rn(o0, h0);   // .x=f(e), .y=f(e+1)
        __half2 p1 = __floats2half2_rn(o1, h1);
        __half2 p2 = __floats2half2_rn(o2, h2);
        tab_g[         e] = *reinterpret_cast<unsigned*>(&p0);
        tab_g[TN     + e] = *reinterpret_cast<unsigned*>(&p1);
        tab_g[2 * TN + e] = *reinterpret_cast<unsigned*>(&p2);
    }
}

__device__ __forceinline__ void lerp3s(
    const unsigned* __restrict__ t0, const unsigned* __restrict__ t1,
    const unsigned* __restrict__ t2, float inv_h, float x,
    float& y0, float& y1, float& y2)
{
    float xc = fminf(fmaxf(x, XLO), XHI);
    float f  = (xc - XLO) * inv_h;
    int i0 = (int)f;
    i0 = min(i0, TN - 2);
    float fr = f - (float)i0;
    unsigned e0 = t0[i0];
    unsigned e1 = t1[i0];
    unsigned e2 = t2[i0];
    float2 p0 = __half22float2(*reinterpret_cast<__half2*>(&e0));
    float2 p1 = __half22float2(*reinterpret_cast<__half2*>(&e1));
    float2 p2 = __half22float2(*reinterpret_cast<__half2*>(&e2));
    y0 = fmaf(fr, p0.y - p0.x, p0.x);
    y1 = fmaf(fr, p1.y - p1.x, p1.x);
    y2 = fmaf(fr, p2.y - p2.x, p2.x);
}

__global__ __launch_bounds__(256) void apply_s(
    const float* __restrict__ x, const unsigned* __restrict__ tab_g,
    float4* __restrict__ out4, unsigned n_out4)
{
    __shared__ __align__(16) unsigned tab[3 * TN];
    {
        uint4* dst = (uint4*)tab;
        const uint4* src = (const uint4*)tab_g;
        for (int i = threadIdx.x; i < 3 * TN / 4; i += 256) dst[i] = src[i];
    }
    __syncthreads();
    const unsigned* t0 = tab;
    const unsigned* t1 = tab + TN;
    const unsigned* t2 = tab + 2 * TN;

    const float inv_h = (float)(TN - 1) / (XHI - XLO);
    unsigned stride = gridDim.x * 256u;
    for (unsigned g = blockIdx.x * 256u + threadIdx.x; g < n_out4; g += stride) {
        unsigned e = (4u * g) / 3u;
        unsigned r = 4u * g - 3u * e;
        float x0 = x[e];
        float x1 = x[e + 1];
        float s0, s1, s2, s3, s4, s5;
        lerp3s(t0, t1, t2, inv_h, x0, s0, s1, s2);
        lerp3s(t0, t1, t2, inv_h, x1, s3, s4, s5);
        f32x4 o;
        o.x = (r == 0u) ? s0 : ((r == 1u) ? s1 : s2);
        o.y = (r == 0u) ? s1 : ((r == 1u) ? s2 : s3);
        o.z = (r == 0u) ? s2 : ((r == 1u) ? s3 : s4);
        o.w = (r == 0u) ? s3 : ((r == 1u) ? s4 : s5);
        __builtin_nontemporal_store(o, (f32x4*)(out4 + g));
    }
}

extern "C" void kernel_launch(void* const* d_in, const int* in_sizes, int n_in,
                              void* d_out, int out_size, void* d_ws, size_t ws_size,
                              hipStream_t stream) {
    const float* x  = (const float*)d_in[0];
    const float* W0 = (const float*)d_in[1];
    const float* b0 = (const float*)d_in[2];
    const float* W1 = (const float*)d_in[3];
    const float* b1 = (const float*)d_in[4];
    const float* W2 = (const float*)d_in[5];
    const float* b2 = (const float*)d_in[6];
    const float* W3 = (const float*)d_in[7];
    const float* b3 = (const float*)d_in[8];
    const float* W4 = (const float*)d_in[9];
    const float* b4 = (const float*)d_in[10];
    unsigned* tab = (unsigned*)d_ws;   // 3*TN*4 = 24 KB scratch

    build_table<<<TN / 4, 256, 0, stream>>>(
        W0, b0, W1, b1, W2, b2, W3, b3, W4, b4, tab);

    unsigned n_out4 = (unsigned)out_size / 4u;   // 3145728
    int blocks = 1536;                           // 6 blocks/CU (24KB LDS)
    apply_s<<<blocks, 256, 0, stream>>>(
        x, tab, (float4*)d_out, n_out4);
}